// Round 1
// baseline (10084.098 us; speedup 1.0000x reference)
//
#include <hip/hip_runtime.h>
#include <cstdint>
#include <cstddef>

#define HDIM 128
#define INDIM 256
#define RANK 4
#define NLAYER 2
#define PELEN 2000
#define HP 132      // padded LDS row (128+4) -> conflict-free across row groups
#define INP 260     // padded LDS row (256+4)

constexpr float SCALING_F = 2.0f;   // 8.0/4.0
constexpr float EPS_LN = 1e-5f;

// ---------------- degree / norm ----------------

__global__ void deg_kernel(const int* __restrict__ src, const int* __restrict__ dst,
                           int* __restrict__ dego, int* __restrict__ degi, int E) {
    int e = blockIdx.x * 256 + threadIdx.x;
    if (e < E) {
        atomicAdd(&dego[src[e]], 1);
        atomicAdd(&degi[dst[e]], 1);
    }
}

__global__ void norm_kernel(const int* __restrict__ dego, const int* __restrict__ degi,
                            float* __restrict__ nout, float* __restrict__ nin, int N) {
    int i = blockIdx.x * 256 + threadIdx.x;
    if (i < N) {
        int a = dego[i];
        nout[i] = (a > 0) ? rsqrtf((float)a) : 0.0f;
        int b = degi[i];
        nin[i]  = (b > 0) ? rsqrtf((float)b) : 0.0f;
    }
}

// ---------------- input projection: h = feats@W_in.T + b_in + lora + pe ----------------

__global__ __launch_bounds__(256) void input_kernel(
        const float* __restrict__ feats, const float* __restrict__ pe,
        const float* __restrict__ Win, const float* __restrict__ bin,
        const float* __restrict__ Ain, const float* __restrict__ Bin,
        float* __restrict__ h, int N) {
    __shared__ float fs[16][INP];
    int brow = blockIdx.x * 16;
    int tid = threadIdx.x;

    // stage 16 feature rows (16*64 float4, 4 per thread)
    {
        const float4* src = (const float4*)(feats + (size_t)brow * INDIM);
        for (int i = tid; i < 16 * (INDIM / 4); i += 256) {
            int row = i >> 6, c4 = i & 63;
            *(float4*)&fs[row][c4 * 4] = src[(size_t)row * (INDIM / 4) + c4];
        }
    }
    __syncthreads();

    int row_l = tid >> 4;       // 0..15
    int tsub  = tid & 15;       // 0..15
    int row   = brow + row_l;
    const float* f = fs[row_l];
    const float4* f4 = (const float4*)f;

    // cooperative LoRA t[r] = sum_k f[k]*A[r][k]  (each tsub covers 16 k's)
    float t[RANK];
#pragma unroll
    for (int r = 0; r < RANK; ++r) {
        const float* Ar = Ain + r * INDIM;
        float p = 0.f;
#pragma unroll
        for (int kk = 0; kk < 16; ++kk) { int k = tsub * 16 + kk; p += f[k] * Ar[k]; }
#pragma unroll
        for (int m = 8; m >= 1; m >>= 1) p += __shfl_xor(p, m);
        t[r] = p;
    }

    int c0 = tsub * 8;
    int pos = (row < PELEN) ? row : (PELEN - 1);
    const float* per = pe + (size_t)pos * HDIM;

    float acc[8];
#pragma unroll
    for (int j = 0; j < 8; ++j) {
        int c = c0 + j;
        float s = bin[c] + per[c];
#pragma unroll
        for (int r = 0; r < RANK; ++r) s += SCALING_F * t[r] * Bin[c * RANK + r];
        acc[j] = s;
    }

    // main matmul: acc[j] += sum_k f[k] * Win[(c0+j)*INDIM + k], k-outer for f reuse
    for (int k4 = 0; k4 < INDIM / 4; ++k4) {
        float4 fv = f4[k4];
#pragma unroll
        for (int j = 0; j < 8; ++j) {
            float4 w = *(const float4*)(Win + (size_t)(c0 + j) * INDIM + k4 * 4);
            acc[j] += fv.x * w.x + fv.y * w.y + fv.z * w.z + fv.w * w.w;
        }
    }

    float* ho = h + (size_t)row * HDIM + c0;
    *(float4*)(ho)     = make_float4(acc[0], acc[1], acc[2], acc[3]);
    *(float4*)(ho + 4) = make_float4(acc[4], acc[5], acc[6], acc[7]);
}

// ---------------- edge scatter: agg[dst] += h[src] * norm_out[src] ----------------

__global__ __launch_bounds__(256) void scatter_kernel(
        const float* __restrict__ h, const float* __restrict__ nout,
        const int* __restrict__ src, const int* __restrict__ dst,
        float* __restrict__ agg, int E) {
    long long gtid = (long long)blockIdx.x * 256 + threadIdx.x;
    int e = (int)(gtid >> 5);
    int lane = (int)(gtid & 31);
    if (e >= E) return;
    int s = src[e], d = dst[e];
    float no = nout[s];
    float4 v = *(const float4*)(h + (size_t)s * HDIM + lane * 4);
    float* out = agg + (size_t)d * HDIM + lane * 4;
    atomicAdd(out + 0, v.x * no);
    atomicAdd(out + 1, v.y * no);
    atomicAdd(out + 2, v.z * no);
    atomicAdd(out + 3, v.w * no);
}

// ---------------- fused layer: h += gelu(LN(gc + lora)) ----------------

__global__ __launch_bounds__(256) void layer_kernel(
        float* __restrict__ h, const float* __restrict__ agg,
        const float* __restrict__ nin,
        const float* __restrict__ gW, const float* __restrict__ gb,
        const float* __restrict__ lWp, const float* __restrict__ lbp,
        const float* __restrict__ lAp, const float* __restrict__ lBp,
        const float* __restrict__ gammap, const float* __restrict__ betap, int N) {
    __shared__ float hs[16][HP];
    __shared__ float as[16][HP];
    int brow = blockIdx.x * 16;
    int tid = threadIdx.x;

    {
        const float4* hsrc = (const float4*)(h + (size_t)brow * HDIM);
        const float4* asrc = (const float4*)(agg + (size_t)brow * HDIM);
        for (int i = tid; i < 16 * (HDIM / 4); i += 256) {
            int row = i >> 5, c4 = i & 31;
            *(float4*)&hs[row][c4 * 4] = hsrc[(size_t)row * (HDIM / 4) + c4];
            float4 a = asrc[(size_t)row * (HDIM / 4) + c4];
            float ni = nin[brow + row];
            a.x *= ni; a.y *= ni; a.z *= ni; a.w *= ni;
            *(float4*)&as[row][c4 * 4] = a;
        }
    }
    __syncthreads();

    int row_l = tid >> 4, tsub = tid & 15;
    const float* hr = hs[row_l];
    const float* ar = as[row_l];
    const float4* h4 = (const float4*)hr;

    // cooperative LoRA t[r] = sum_k hr[k]*lA[r][k]  (each tsub covers 8 k's)
    float t[RANK];
#pragma unroll
    for (int r = 0; r < RANK; ++r) {
        const float* Ar = lAp + r * HDIM;
        float p = 0.f;
#pragma unroll
        for (int kk = 0; kk < 8; ++kk) { int k = tsub * 8 + kk; p += hr[k] * Ar[k]; }
#pragma unroll
        for (int m = 8; m >= 1; m >>= 1) p += __shfl_xor(p, m);
        t[r] = p;
    }

    int c0 = tsub * 8;
    float acc[8];
#pragma unroll
    for (int j = 0; j < 8; ++j) {
        int c = c0 + j;
        float s = gb[c] + lbp[c];
#pragma unroll
        for (int r = 0; r < RANK; ++r) s += SCALING_F * t[r] * lBp[c * RANK + r];
        acc[j] = s;
    }

    // graph-conv matmul: acc[j] += sum_k ar[k]*gW[k*H + c0+j]  (coalesced rows of gW)
    for (int k = 0; k < HDIM; ++k) {
        float av = ar[k];
        const float4* wrow = (const float4*)(gW + (size_t)k * HDIM + c0);
        float4 w0 = wrow[0], w1 = wrow[1];
        acc[0] += av * w0.x; acc[1] += av * w0.y; acc[2] += av * w0.z; acc[3] += av * w0.w;
        acc[4] += av * w1.x; acc[5] += av * w1.y; acc[6] += av * w1.z; acc[7] += av * w1.w;
    }

    // lora main: acc[j] += sum_k hr[k]*lW[(c0+j)*H + k], k-outer
    for (int k4 = 0; k4 < HDIM / 4; ++k4) {
        float4 hv = h4[k4];
#pragma unroll
        for (int j = 0; j < 8; ++j) {
            float4 w = *(const float4*)(lWp + (size_t)(c0 + j) * HDIM + k4 * 4);
            acc[j] += hv.x * w.x + hv.y * w.y + hv.z * w.z + hv.w * w.w;
        }
    }

    // LayerNorm over 128 (16 threads x 8), two-pass for accuracy
    float ssum = 0.f;
#pragma unroll
    for (int j = 0; j < 8; ++j) ssum += acc[j];
#pragma unroll
    for (int m = 8; m >= 1; m >>= 1) ssum += __shfl_xor(ssum, m);
    float mu = ssum * (1.0f / HDIM);
    float vsum = 0.f;
#pragma unroll
    for (int j = 0; j < 8; ++j) { float d = acc[j] - mu; vsum += d * d; }
#pragma unroll
    for (int m = 8; m >= 1; m >>= 1) vsum += __shfl_xor(vsum, m);
    float rstd = rsqrtf(vsum * (1.0f / HDIM) + EPS_LN);

    float* ho = h + (size_t)(brow + row_l) * HDIM + c0;
    float o[8];
#pragma unroll
    for (int j = 0; j < 8; ++j) {
        int c = c0 + j;
        float y = (acc[j] - mu) * rstd * gammap[c] + betap[c];
        float g = 0.5f * y * (1.0f + erff(y * 0.70710678118654752f));
        o[j] = hr[c] + g;   // residual
    }
    *(float4*)(ho)     = make_float4(o[0], o[1], o[2], o[3]);
    *(float4*)(ho + 4) = make_float4(o[4], o[5], o[6], o[7]);
}

// ---------------- output projection ----------------

__global__ __launch_bounds__(256) void out_kernel(
        const float* __restrict__ h,
        const float* __restrict__ W, const float* __restrict__ b,
        const float* __restrict__ A, const float* __restrict__ B,
        float* __restrict__ out, int N) {
    __shared__ float hs[16][HP];
    int brow = blockIdx.x * 16;
    int tid = threadIdx.x;
    {
        const float4* hsrc = (const float4*)(h + (size_t)brow * HDIM);
        for (int i = tid; i < 16 * (HDIM / 4); i += 256) {
            int row = i >> 5, c4 = i & 31;
            *(float4*)&hs[row][c4 * 4] = hsrc[(size_t)row * (HDIM / 4) + c4];
        }
    }
    __syncthreads();

    int row_l = tid >> 4, tsub = tid & 15;
    const float* hr = hs[row_l];
    const float4* h4 = (const float4*)hr;

    float t[RANK];
#pragma unroll
    for (int r = 0; r < RANK; ++r) {
        const float* Ar = A + r * HDIM;
        float p = 0.f;
#pragma unroll
        for (int kk = 0; kk < 8; ++kk) { int k = tsub * 8 + kk; p += hr[k] * Ar[k]; }
#pragma unroll
        for (int m = 8; m >= 1; m >>= 1) p += __shfl_xor(p, m);
        t[r] = p;
    }

    int c0 = tsub * 8;
    float acc[8];
#pragma unroll
    for (int j = 0; j < 8; ++j) {
        int c = c0 + j;
        float s = b[c];
#pragma unroll
        for (int r = 0; r < RANK; ++r) s += SCALING_F * t[r] * B[c * RANK + r];
        acc[j] = s;
    }

    for (int k4 = 0; k4 < HDIM / 4; ++k4) {
        float4 hv = h4[k4];
#pragma unroll
        for (int j = 0; j < 8; ++j) {
            float4 w = *(const float4*)(W + (size_t)(c0 + j) * HDIM + k4 * 4);
            acc[j] += hv.x * w.x + hv.y * w.y + hv.z * w.z + hv.w * w.w;
        }
    }

    float* oo = out + (size_t)(brow + row_l) * HDIM + c0;
    *(float4*)(oo)     = make_float4(acc[0], acc[1], acc[2], acc[3]);
    *(float4*)(oo + 4) = make_float4(acc[4], acc[5], acc[6], acc[7]);
}

// ---------------- launch ----------------

extern "C" void kernel_launch(void* const* d_in, const int* in_sizes, int n_in,
                              void* d_out, int out_size, void* d_ws, size_t ws_size,
                              hipStream_t stream) {
    const float* features = (const float*)d_in[0];
    const int*   esrc     = (const int*)d_in[1];
    const int*   edst     = (const int*)d_in[2];
    const float* pe       = (const float*)d_in[3];
    const float* W_in     = (const float*)d_in[4];
    const float* b_in     = (const float*)d_in[5];
    const float* A_in     = (const float*)d_in[6];
    const float* B_in     = (const float*)d_in[7];
    const float* gnn_W    = (const float*)d_in[8];
    const float* gnn_b    = (const float*)d_in[9];
    const float* lW       = (const float*)d_in[10];
    const float* lb       = (const float*)d_in[11];
    const float* lA       = (const float*)d_in[12];
    const float* lB       = (const float*)d_in[13];
    const float* gamma    = (const float*)d_in[14];
    const float* beta     = (const float*)d_in[15];
    const float* W_out    = (const float*)d_in[16];
    const float* b_out    = (const float*)d_in[17];
    const float* A_out    = (const float*)d_in[18];
    const float* B_out    = (const float*)d_in[19];

    int N = in_sizes[0] / INDIM;   // 100000
    int E = in_sizes[1];           // 1,700,000

    // workspace layout
    char* ws = (char*)d_ws;
    float* h    = (float*)ws;                              // N*H floats
    float* agg  = h + (size_t)N * HDIM;                    // N*H floats
    int*   dego = (int*)(agg + (size_t)N * HDIM);          // N ints
    int*   degi = dego + N;                                // N ints
    float* nout = (float*)(degi + N);                      // N floats
    float* nin  = nout + N;                                // N floats

    // degrees + norms (used by both layers)
    hipMemsetAsync(dego, 0, 2 * (size_t)N * sizeof(int), stream);
    deg_kernel<<<(E + 255) / 256, 256, 0, stream>>>(esrc, edst, dego, degi, E);
    norm_kernel<<<(N + 255) / 256, 256, 0, stream>>>(dego, degi, nout, nin, N);

    // input projection + PE
    input_kernel<<<N / 16, 256, 0, stream>>>(features, pe, W_in, b_in, A_in, B_in, h, N);

    for (int i = 0; i < NLAYER; ++i) {
        hipMemsetAsync(agg, 0, (size_t)N * HDIM * sizeof(float), stream);
        scatter_kernel<<<(int)(((long long)E * 32 + 255) / 256), 256, 0, stream>>>(
            h, nout, esrc, edst, agg, E);
        layer_kernel<<<N / 16, 256, 0, stream>>>(
            h, agg, nin,
            gnn_W + (size_t)i * HDIM * HDIM, gnn_b + (size_t)i * HDIM,
            lW + (size_t)i * HDIM * HDIM, lb + (size_t)i * HDIM,
            lA + (size_t)i * RANK * HDIM, lB + (size_t)i * HDIM * RANK,
            gamma + (size_t)i * HDIM, beta + (size_t)i * HDIM, N);
    }

    out_kernel<<<N / 16, 256, 0, stream>>>(h, W_out, b_out, A_out, B_out, (float*)d_out, N);
}

// Round 2
// 4736.070 us; speedup vs baseline: 2.1292x; 2.1292x over previous
//
#include <hip/hip_runtime.h>
#include <cstdint>
#include <cstddef>

#define HDIM 128
#define INDIM 256
#define RANK 4
#define NLAYER 2
#define PELEN 2000
#define HP 132      // padded LDS row (128+4)
#define INP 260     // padded LDS row (256+4)

constexpr float SCALING_F = 2.0f;   // 8.0/4.0
constexpr float EPS_LN = 1e-5f;

// ---------------- degree ----------------

__global__ void deg_kernel(const int* __restrict__ src, const int* __restrict__ dst,
                           int* __restrict__ dego, int* __restrict__ degi, int E) {
    int e = blockIdx.x * 256 + threadIdx.x;
    if (e < E) {
        atomicAdd(&dego[src[e]], 1);
        atomicAdd(&degi[dst[e]], 1);
    }
}

__global__ void norm_kernel(const int* __restrict__ dego, const int* __restrict__ degi,
                            float* __restrict__ nout, float* __restrict__ nin, int N) {
    int i = blockIdx.x * 256 + threadIdx.x;
    if (i < N) {
        int a = dego[i];
        nout[i] = (a > 0) ? rsqrtf((float)a) : 0.0f;
        int b = degi[i];
        nin[i]  = (b > 0) ? rsqrtf((float)b) : 0.0f;
    }
}

// ---------------- exclusive scan of degi -> row_ptr / cursor ----------------

__global__ __launch_bounds__(256) void scan1_kernel(const int* __restrict__ degi,
                                                    int* __restrict__ sincl,
                                                    int* __restrict__ bsum, int N) {
    int i = blockIdx.x * 256 + threadIdx.x;
    int lane = threadIdx.x & 63;
    int w = threadIdx.x >> 6;
    int x = (i < N) ? degi[i] : 0;
#pragma unroll
    for (int d = 1; d < 64; d <<= 1) {
        int y = __shfl_up(x, d);
        if (lane >= d) x += y;
    }
    __shared__ int wsum[4];
    if (lane == 63) wsum[w] = x;
    __syncthreads();
    int add = 0;
    for (int j = 0; j < w; ++j) add += wsum[j];
    x += add;
    if (i < N) sincl[i] = x;
    if (threadIdx.x == 255) bsum[blockIdx.x] = x;
}

__global__ __launch_bounds__(512) void scan2_kernel(int* __restrict__ bsum, int NB) {
    int i = threadIdx.x;
    int lane = i & 63;
    int w = i >> 6;
    int x = (i < NB) ? bsum[i] : 0;
#pragma unroll
    for (int d = 1; d < 64; d <<= 1) {
        int y = __shfl_up(x, d);
        if (lane >= d) x += y;
    }
    __shared__ int wsum[8];
    if (lane == 63) wsum[w] = x;
    __syncthreads();
    int add = 0;
    for (int j = 0; j < w; ++j) add += wsum[j];
    x += add;
    if (i < NB) bsum[i] = x;
}

__global__ __launch_bounds__(256) void scan3_kernel(const int* __restrict__ degi,
                                                    const int* __restrict__ sincl,
                                                    const int* __restrict__ bsum,
                                                    int* __restrict__ row_ptr,
                                                    int* __restrict__ cursor, int N) {
    int i = blockIdx.x * 256 + threadIdx.x;
    if (i >= N) return;
    int b = blockIdx.x;
    int incl = sincl[i] + ((b > 0) ? bsum[b - 1] : 0);
    int excl = incl - degi[i];
    row_ptr[i] = excl;
    cursor[i] = excl;
    if (i == N - 1) row_ptr[N] = incl;
}

__global__ void place_kernel(const int* __restrict__ src, const int* __restrict__ dst,
                             int* __restrict__ cursor, int* __restrict__ csr_src, int E) {
    int e = blockIdx.x * 256 + threadIdx.x;
    if (e < E) {
        int d = dst[e];
        int pos = atomicAdd(&cursor[d], 1);
        csr_src[pos] = src[e];
    }
}

// ---------------- per-node gather: agg[n] = nin[n] * sum_{e: dst=n} h[src]*nout[src] ----------------

__global__ __launch_bounds__(256) void gather_kernel(
        const float* __restrict__ h, const float* __restrict__ nout,
        const float* __restrict__ nin, const int* __restrict__ row_ptr,
        const int* __restrict__ csr_src, float* __restrict__ agg, int N) {
    int node = blockIdx.x * 4 + (threadIdx.x >> 6);
    if (node >= N) return;
    int lane = threadIdx.x & 63;
    int start = row_ptr[node], end = row_ptr[node + 1];
    const float2* h2 = (const float2*)h;
    float2 acc = make_float2(0.f, 0.f);
    int i = start;
    for (; i + 2 <= end; i += 2) {
        int s0 = csr_src[i], s1 = csr_src[i + 1];
        float n0 = nout[s0], n1 = nout[s1];
        float2 v0 = h2[(size_t)s0 * 64 + lane];
        float2 v1 = h2[(size_t)s1 * 64 + lane];
        acc.x += v0.x * n0; acc.y += v0.y * n0;
        acc.x += v1.x * n1; acc.y += v1.y * n1;
    }
    if (i < end) {
        int s = csr_src[i];
        float n = nout[s];
        float2 v = h2[(size_t)s * 64 + lane];
        acc.x += v.x * n; acc.y += v.y * n;
    }
    float ni = nin[node];
    ((float2*)agg)[(size_t)node * 64 + lane] = make_float2(acc.x * ni, acc.y * ni);
}

// ---------------- input projection: h = feats@W_in.T + b_in + lora + pe ----------------

__global__ __launch_bounds__(256) void input_kernel(
        const float* __restrict__ feats, const float* __restrict__ pe,
        const float* __restrict__ Win, const float* __restrict__ bin,
        const float* __restrict__ Ain, const float* __restrict__ Bin,
        float* __restrict__ h, int N) {
    __shared__ float fs[16][INP];
    int brow = blockIdx.x * 16;
    int tid = threadIdx.x;

    {
        const float4* src = (const float4*)(feats + (size_t)brow * INDIM);
        for (int i = tid; i < 16 * (INDIM / 4); i += 256) {
            int row = i >> 6, c4 = i & 63;
            *(float4*)&fs[row][c4 * 4] = src[(size_t)row * (INDIM / 4) + c4];
        }
    }
    __syncthreads();

    int row_l = tid >> 4;
    int tsub  = tid & 15;
    int row   = brow + row_l;
    const float* f = fs[row_l];
    const float4* f4 = (const float4*)f;

    float t[RANK];
#pragma unroll
    for (int r = 0; r < RANK; ++r) {
        const float* Ar = Ain + r * INDIM;
        float p = 0.f;
#pragma unroll
        for (int kk = 0; kk < 16; ++kk) { int k = tsub * 16 + kk; p += f[k] * Ar[k]; }
#pragma unroll
        for (int m = 8; m >= 1; m >>= 1) p += __shfl_xor(p, m);
        t[r] = p;
    }

    int c0 = tsub * 8;
    int pos = (row < PELEN) ? row : (PELEN - 1);
    const float* per = pe + (size_t)pos * HDIM;

    float acc[8];
#pragma unroll
    for (int j = 0; j < 8; ++j) {
        int c = c0 + j;
        float s = bin[c] + per[c];
#pragma unroll
        for (int r = 0; r < RANK; ++r) s += SCALING_F * t[r] * Bin[c * RANK + r];
        acc[j] = s;
    }

    for (int k4 = 0; k4 < INDIM / 4; ++k4) {
        float4 fv = f4[k4];
#pragma unroll
        for (int j = 0; j < 8; ++j) {
            float4 w = *(const float4*)(Win + (size_t)(c0 + j) * INDIM + k4 * 4);
            acc[j] += fv.x * w.x + fv.y * w.y + fv.z * w.z + fv.w * w.w;
        }
    }

    float* ho = h + (size_t)row * HDIM + c0;
    *(float4*)(ho)     = make_float4(acc[0], acc[1], acc[2], acc[3]);
    *(float4*)(ho + 4) = make_float4(acc[4], acc[5], acc[6], acc[7]);
}

// ---------------- fused layer: h += gelu(LN(gc + lora)) ----------------

__global__ __launch_bounds__(256) void layer_kernel(
        float* __restrict__ h, const float* __restrict__ agg,
        const float* __restrict__ gW, const float* __restrict__ gb,
        const float* __restrict__ lWp, const float* __restrict__ lbp,
        const float* __restrict__ lAp, const float* __restrict__ lBp,
        const float* __restrict__ gammap, const float* __restrict__ betap, int N) {
    __shared__ float hs[16][HP];
    __shared__ float as[16][HP];
    int brow = blockIdx.x * 16;
    int tid = threadIdx.x;

    {
        const float4* hsrc = (const float4*)(h + (size_t)brow * HDIM);
        const float4* asrc = (const float4*)(agg + (size_t)brow * HDIM);
        for (int i = tid; i < 16 * (HDIM / 4); i += 256) {
            int row = i >> 5, c4 = i & 31;
            *(float4*)&hs[row][c4 * 4] = hsrc[(size_t)row * (HDIM / 4) + c4];
            *(float4*)&as[row][c4 * 4] = asrc[(size_t)row * (HDIM / 4) + c4];
        }
    }
    __syncthreads();

    int row_l = tid >> 4, tsub = tid & 15;
    const float* hr = hs[row_l];
    const float* ar = as[row_l];
    const float4* h4 = (const float4*)hr;

    float t[RANK];
#pragma unroll
    for (int r = 0; r < RANK; ++r) {
        const float* Ar = lAp + r * HDIM;
        float p = 0.f;
#pragma unroll
        for (int kk = 0; kk < 8; ++kk) { int k = tsub * 8 + kk; p += hr[k] * Ar[k]; }
#pragma unroll
        for (int m = 8; m >= 1; m >>= 1) p += __shfl_xor(p, m);
        t[r] = p;
    }

    int c0 = tsub * 8;
    float acc[8];
#pragma unroll
    for (int j = 0; j < 8; ++j) {
        int c = c0 + j;
        float s = gb[c] + lbp[c];
#pragma unroll
        for (int r = 0; r < RANK; ++r) s += SCALING_F * t[r] * lBp[c * RANK + r];
        acc[j] = s;
    }

    for (int k = 0; k < HDIM; ++k) {
        float av = ar[k];
        const float4* wrow = (const float4*)(gW + (size_t)k * HDIM + c0);
        float4 w0 = wrow[0], w1 = wrow[1];
        acc[0] += av * w0.x; acc[1] += av * w0.y; acc[2] += av * w0.z; acc[3] += av * w0.w;
        acc[4] += av * w1.x; acc[5] += av * w1.y; acc[6] += av * w1.z; acc[7] += av * w1.w;
    }

    for (int k4 = 0; k4 < HDIM / 4; ++k4) {
        float4 hv = h4[k4];
#pragma unroll
        for (int j = 0; j < 8; ++j) {
            float4 w = *(const float4*)(lWp + (size_t)(c0 + j) * HDIM + k4 * 4);
            acc[j] += hv.x * w.x + hv.y * w.y + hv.z * w.z + hv.w * w.w;
        }
    }

    float ssum = 0.f;
#pragma unroll
    for (int j = 0; j < 8; ++j) ssum += acc[j];
#pragma unroll
    for (int m = 8; m >= 1; m >>= 1) ssum += __shfl_xor(ssum, m);
    float mu = ssum * (1.0f / HDIM);
    float vsum = 0.f;
#pragma unroll
    for (int j = 0; j < 8; ++j) { float d = acc[j] - mu; vsum += d * d; }
#pragma unroll
    for (int m = 8; m >= 1; m >>= 1) vsum += __shfl_xor(vsum, m);
    float rstd = rsqrtf(vsum * (1.0f / HDIM) + EPS_LN);

    float* ho = h + (size_t)(brow + row_l) * HDIM + c0;
    float o[8];
#pragma unroll
    for (int j = 0; j < 8; ++j) {
        int c = c0 + j;
        float y = (acc[j] - mu) * rstd * gammap[c] + betap[c];
        float g = 0.5f * y * (1.0f + erff(y * 0.70710678118654752f));
        o[j] = hr[c] + g;
    }
    *(float4*)(ho)     = make_float4(o[0], o[1], o[2], o[3]);
    *(float4*)(ho + 4) = make_float4(o[4], o[5], o[6], o[7]);
}

// ---------------- output projection ----------------

__global__ __launch_bounds__(256) void out_kernel(
        const float* __restrict__ h,
        const float* __restrict__ W, const float* __restrict__ b,
        const float* __restrict__ A, const float* __restrict__ B,
        float* __restrict__ out, int N) {
    __shared__ float hs[16][HP];
    int brow = blockIdx.x * 16;
    int tid = threadIdx.x;
    {
        const float4* hsrc = (const float4*)(h + (size_t)brow * HDIM);
        for (int i = tid; i < 16 * (HDIM / 4); i += 256) {
            int row = i >> 5, c4 = i & 31;
            *(float4*)&hs[row][c4 * 4] = hsrc[(size_t)row * (HDIM / 4) + c4];
        }
    }
    __syncthreads();

    int row_l = tid >> 4, tsub = tid & 15;
    const float* hr = hs[row_l];
    const float4* h4 = (const float4*)hr;

    float t[RANK];
#pragma unroll
    for (int r = 0; r < RANK; ++r) {
        const float* Ar = A + r * HDIM;
        float p = 0.f;
#pragma unroll
        for (int kk = 0; kk < 8; ++kk) { int k = tsub * 8 + kk; p += hr[k] * Ar[k]; }
#pragma unroll
        for (int m = 8; m >= 1; m >>= 1) p += __shfl_xor(p, m);
        t[r] = p;
    }

    int c0 = tsub * 8;
    float acc[8];
#pragma unroll
    for (int j = 0; j < 8; ++j) {
        int c = c0 + j;
        float s = b[c];
#pragma unroll
        for (int r = 0; r < RANK; ++r) s += SCALING_F * t[r] * B[c * RANK + r];
        acc[j] = s;
    }

    for (int k4 = 0; k4 < HDIM / 4; ++k4) {
        float4 hv = h4[k4];
#pragma unroll
        for (int j = 0; j < 8; ++j) {
            float4 w = *(const float4*)(W + (size_t)(c0 + j) * HDIM + k4 * 4);
            acc[j] += hv.x * w.x + hv.y * w.y + hv.z * w.z + hv.w * w.w;
        }
    }

    float* oo = out + (size_t)(brow + row_l) * HDIM + c0;
    *(float4*)(oo)     = make_float4(acc[0], acc[1], acc[2], acc[3]);
    *(float4*)(oo + 4) = make_float4(acc[4], acc[5], acc[6], acc[7]);
}

// ---------------- launch ----------------

extern "C" void kernel_launch(void* const* d_in, const int* in_sizes, int n_in,
                              void* d_out, int out_size, void* d_ws, size_t ws_size,
                              hipStream_t stream) {
    const float* features = (const float*)d_in[0];
    const int*   esrc     = (const int*)d_in[1];
    const int*   edst     = (const int*)d_in[2];
    const float* pe       = (const float*)d_in[3];
    const float* W_in     = (const float*)d_in[4];
    const float* b_in     = (const float*)d_in[5];
    const float* A_in     = (const float*)d_in[6];
    const float* B_in     = (const float*)d_in[7];
    const float* gnn_W    = (const float*)d_in[8];
    const float* gnn_b    = (const float*)d_in[9];
    const float* lW       = (const float*)d_in[10];
    const float* lb       = (const float*)d_in[11];
    const float* lA       = (const float*)d_in[12];
    const float* lB       = (const float*)d_in[13];
    const float* gamma    = (const float*)d_in[14];
    const float* beta     = (const float*)d_in[15];
    const float* W_out    = (const float*)d_in[16];
    const float* b_out    = (const float*)d_in[17];
    const float* A_out    = (const float*)d_in[18];
    const float* B_out    = (const float*)d_in[19];

    int N = in_sizes[0] / INDIM;   // 100000
    int E = in_sizes[1];           // 1,700,000
    int NB = (N + 255) / 256;      // scan blocks (391)

    // workspace layout
    char* ws = (char*)d_ws;
    float* h       = (float*)ws;                               // N*H
    float* agg     = h + (size_t)N * HDIM;                     // N*H
    int*   dego    = (int*)(agg + (size_t)N * HDIM);           // N
    int*   degi    = dego + N;                                 // N
    float* nout    = (float*)(degi + N);                       // N
    float* nin     = nout + N;                                 // N
    int*   row_ptr = (int*)(nin + N);                          // N+1
    int*   cursor  = row_ptr + N + 1;                          // N
    int*   sincl   = cursor + N;                               // N
    int*   bsum    = sincl + N;                                // NB
    int*   csr_src = bsum + NB;                                // E

    // degrees + norms
    hipMemsetAsync(dego, 0, 2 * (size_t)N * sizeof(int), stream);
    deg_kernel<<<(E + 255) / 256, 256, 0, stream>>>(esrc, edst, dego, degi, E);
    norm_kernel<<<NB, 256, 0, stream>>>(dego, degi, nout, nin, N);

    // CSR by dst: exclusive scan + placement
    scan1_kernel<<<NB, 256, 0, stream>>>(degi, sincl, bsum, N);
    scan2_kernel<<<1, 512, 0, stream>>>(bsum, NB);
    scan3_kernel<<<NB, 256, 0, stream>>>(degi, sincl, bsum, row_ptr, cursor, N);
    place_kernel<<<(E + 255) / 256, 256, 0, stream>>>(esrc, edst, cursor, csr_src, E);

    // input projection + PE
    input_kernel<<<N / 16, 256, 0, stream>>>(features, pe, W_in, b_in, A_in, B_in, h, N);

    for (int i = 0; i < NLAYER; ++i) {
        gather_kernel<<<(N + 3) / 4, 256, 0, stream>>>(h, nout, nin, row_ptr, csr_src, agg, N);
        layer_kernel<<<N / 16, 256, 0, stream>>>(
            h, agg,
            gnn_W + (size_t)i * HDIM * HDIM, gnn_b + (size_t)i * HDIM,
            lW + (size_t)i * HDIM * HDIM, lb + (size_t)i * HDIM,
            lA + (size_t)i * RANK * HDIM, lB + (size_t)i * HDIM * RANK,
            gamma + (size_t)i * HDIM, beta + (size_t)i * HDIM, N);
    }

    out_kernel<<<N / 16, 256, 0, stream>>>(h, W_out, b_out, A_out, B_out, (float*)d_out, N);
}

// Round 5
// 1191.548 us; speedup vs baseline: 8.4630x; 3.9747x over previous
//
#include <hip/hip_runtime.h>
#include <cstdint>
#include <cstddef>

#define HDIM 128
#define INDIM 256
#define RANK 4
#define NLAYER 2
#define PELEN 2000

#define BM 64
#define BK 32
#define XT_LD 68    // BM + 4 pad
#define WT_LD 132   // 128 + 4 pad

constexpr float SCALING_F = 2.0f;   // 8.0/4.0
constexpr float EPS_LN = 1e-5f;

// ================= graph prep =================

__global__ void deg_kernel(const int* __restrict__ src, const int* __restrict__ dst,
                           int* __restrict__ dego, int* __restrict__ degi, int E) {
    int e = blockIdx.x * 256 + threadIdx.x;
    if (e < E) {
        atomicAdd(&dego[src[e]], 1);
        atomicAdd(&degi[dst[e]], 1);
    }
}

__global__ void norm_kernel(const int* __restrict__ dego, const int* __restrict__ degi,
                            float* __restrict__ nout, float* __restrict__ nin, int N) {
    int i = blockIdx.x * 256 + threadIdx.x;
    if (i < N) {
        int a = dego[i];
        nout[i] = (a > 0) ? rsqrtf((float)a) : 0.0f;
        int b = degi[i];
        nin[i]  = (b > 0) ? rsqrtf((float)b) : 0.0f;
    }
}

__global__ __launch_bounds__(256) void scan1_kernel(const int* __restrict__ degi,
                                                    int* __restrict__ sincl,
                                                    int* __restrict__ bsum, int N) {
    int i = blockIdx.x * 256 + threadIdx.x;
    int lane = threadIdx.x & 63;
    int w = threadIdx.x >> 6;
    int x = (i < N) ? degi[i] : 0;
#pragma unroll
    for (int d = 1; d < 64; d <<= 1) {
        int y = __shfl_up(x, d);
        if (lane >= d) x += y;
    }
    __shared__ int wsum[4];
    if (lane == 63) wsum[w] = x;
    __syncthreads();
    int add = 0;
    for (int j = 0; j < w; ++j) add += wsum[j];
    x += add;
    if (i < N) sincl[i] = x;
    if (threadIdx.x == 255) bsum[blockIdx.x] = x;
}

__global__ __launch_bounds__(512) void scan2_kernel(int* __restrict__ bsum, int NB) {
    int i = threadIdx.x;
    int lane = i & 63;
    int w = i >> 6;
    int x = (i < NB) ? bsum[i] : 0;
#pragma unroll
    for (int d = 1; d < 64; d <<= 1) {
        int y = __shfl_up(x, d);
        if (lane >= d) x += y;
    }
    __shared__ int wsum[8];
    if (lane == 63) wsum[w] = x;
    __syncthreads();
    int add = 0;
    for (int j = 0; j < w; ++j) add += wsum[j];
    x += add;
    if (i < NB) bsum[i] = x;
}

__global__ __launch_bounds__(256) void scan3_kernel(const int* __restrict__ degi,
                                                    const int* __restrict__ sincl,
                                                    const int* __restrict__ bsum,
                                                    int* __restrict__ row_ptr,
                                                    int* __restrict__ cursor, int N) {
    int i = blockIdx.x * 256 + threadIdx.x;
    if (i >= N) return;
    int b = blockIdx.x;
    int incl = sincl[i] + ((b > 0) ? bsum[b - 1] : 0);
    int excl = incl - degi[i];
    row_ptr[i] = excl;
    cursor[i] = excl;
    if (i == N - 1) row_ptr[N] = incl;
}

__global__ void place_kernel(const int* __restrict__ src, const int* __restrict__ dst,
                             int* __restrict__ cursor, int* __restrict__ csr_src, int E) {
    int e = blockIdx.x * 256 + threadIdx.x;
    if (e < E) {
        int d = dst[e];
        int pos = atomicAdd(&cursor[d], 1);
        csr_src[pos] = src[e];
    }
}

// agg[n] = nin[n] * sum_{e: dst=n} h[src]*nout[src]
__global__ __launch_bounds__(256) void gather_kernel(
        const float* __restrict__ h, const float* __restrict__ nout,
        const float* __restrict__ nin, const int* __restrict__ row_ptr,
        const int* __restrict__ csr_src, float* __restrict__ agg, int N) {
    int node = blockIdx.x * 4 + (threadIdx.x >> 6);
    if (node >= N) return;
    int lane = threadIdx.x & 63;
    int start = row_ptr[node], end = row_ptr[node + 1];
    const float2* h2 = (const float2*)h;
    float2 acc = make_float2(0.f, 0.f);
    int i = start;
    for (; i + 2 <= end; i += 2) {
        int s0 = csr_src[i], s1 = csr_src[i + 1];
        float n0 = nout[s0], n1 = nout[s1];
        float2 v0 = h2[(size_t)s0 * 64 + lane];
        float2 v1 = h2[(size_t)s1 * 64 + lane];
        acc.x += v0.x * n0; acc.y += v0.y * n0;
        acc.x += v1.x * n1; acc.y += v1.y * n1;
    }
    if (i < end) {
        int s = csr_src[i];
        float n = nout[s];
        float2 v = h2[(size_t)s * 64 + lane];
        acc.x += v.x * n; acc.y += v.y * n;
    }
    float ni = nin[node];
    ((float2*)agg)[(size_t)node * 64 + lane] = make_float2(acc.x * ni, acc.y * ni);
}

// ================= tiled GEMM building blocks =================

// stage X[brow..brow+63][k0..k0+31] -> xt[kk][row] (transposed)
__device__ __forceinline__ void stage_x(const float* __restrict__ X, int ldx, int brow,
                                        int k0, int N, int tid, float xt[BK][XT_LD]) {
    int rr = tid & 63;        // row within tile
    int kc = tid >> 6;        // 0..3, 8-float column chunk
    int row = brow + rr;
    float4 v0 = make_float4(0.f, 0.f, 0.f, 0.f), v1 = v0;
    if (row < N) {
        const float4* s = (const float4*)(X + (size_t)row * ldx + k0 + kc * 8);
        v0 = s[0]; v1 = s[1];
    }
    int kb = kc * 8;
    xt[kb + 0][rr] = v0.x; xt[kb + 1][rr] = v0.y; xt[kb + 2][rr] = v0.z; xt[kb + 3][rr] = v0.w;
    xt[kb + 4][rr] = v1.x; xt[kb + 5][rr] = v1.y; xt[kb + 6][rr] = v1.z; xt[kb + 7][rr] = v1.w;
}

// stage W[n][k0..k0+31] ([128][ldw] row-major, used as x@W.T) -> wt[kk][n]
__device__ __forceinline__ void stage_wT(const float* __restrict__ W, int ldw,
                                         int k0, int tid, float wt[BK][WT_LD]) {
    int n = tid >> 1, half = tid & 1;
    const float4* s = (const float4*)(W + (size_t)n * ldw + k0 + half * 16);
    float4 a = s[0], b = s[1], c = s[2], d = s[3];
    int kb = half * 16;
    wt[kb +  0][n] = a.x; wt[kb +  1][n] = a.y; wt[kb +  2][n] = a.z; wt[kb +  3][n] = a.w;
    wt[kb +  4][n] = b.x; wt[kb +  5][n] = b.y; wt[kb +  6][n] = b.z; wt[kb +  7][n] = b.w;
    wt[kb +  8][n] = c.x; wt[kb +  9][n] = c.y; wt[kb + 10][n] = c.z; wt[kb + 11][n] = c.w;
    wt[kb + 12][n] = d.x; wt[kb + 13][n] = d.y; wt[kb + 14][n] = d.z; wt[kb + 15][n] = d.w;
}

// stage W[k0..k0+31][0..127] ([K][128] row-major, used as x@W) -> wt[kk][n]
__device__ __forceinline__ void stage_wD(const float* __restrict__ W,
                                         int k0, int tid, float wt[BK][WT_LD]) {
    int kk = tid >> 3, nc = tid & 7;
    const float4* s = (const float4*)(W + (size_t)(k0 + kk) * HDIM);
#pragma unroll
    for (int j = 0; j < 4; ++j) {
        float4 v = s[nc + 8 * j];
        *(float4*)&wt[kk][(nc + 8 * j) * 4] = v;
    }
}

// inner: acc[4][8] += xt[k][r0..r0+3] x wt[k][c0..c0+7]
__device__ __forceinline__ void mm_inner(const float xt[BK][XT_LD], const float wt[BK][WT_LD],
                                         int r0, int c0, float acc[4][8]) {
#pragma unroll
    for (int kk = 0; kk < BK; ++kk) {
        float4 a  = *(const float4*)&xt[kk][r0];
        float4 b0 = *(const float4*)&wt[kk][c0];
        float4 b1 = *(const float4*)&wt[kk][c0 + 4];
        float av[4] = {a.x, a.y, a.z, a.w};
        float bv[8] = {b0.x, b0.y, b0.z, b0.w, b1.x, b1.y, b1.z, b1.w};
#pragma unroll
        for (int i = 0; i < 4; ++i)
#pragma unroll
            for (int j = 0; j < 8; ++j)
                acc[i][j] = fmaf(av[i], bv[j], acc[i][j]);
    }
}

// lora partial: tacc += sum_kk xt[kk][lrow] * A[lq][k0+kk]
__device__ __forceinline__ float lora_part(const float xt[BK][XT_LD],
                                           const float* __restrict__ A, int ldA,
                                           int k0, int lrow, int lq) {
    const float* Arow = A + (size_t)lq * ldA + k0;
    float p = 0.f;
#pragma unroll
    for (int q4 = 0; q4 < BK / 4; ++q4) {
        float4 av = *(const float4*)(Arow + q4 * 4);
        p = fmaf(xt[q4 * 4 + 0][lrow], av.x, p);
        p = fmaf(xt[q4 * 4 + 1][lrow], av.y, p);
        p = fmaf(xt[q4 * 4 + 2][lrow], av.z, p);
        p = fmaf(xt[q4 * 4 + 3][lrow], av.w, p);
    }
    return p;
}

// ================= input projection =================
// h = feats@Win.T + bin + SCALING*(feats@Ain.T)@Bin.T + pe[min(row,1999)]

__global__ __launch_bounds__(256) void input_kernel(
        const float* __restrict__ feats, const float* __restrict__ pe,
        const float* __restrict__ Win, const float* __restrict__ bin,
        const float* __restrict__ Ain, const float* __restrict__ Bin,
        float* __restrict__ h, int N) {
    __shared__ float xt[BK][XT_LD];
    __shared__ float wt[BK][WT_LD];
    __shared__ float ts[BM][RANK];
    int brow = blockIdx.x * BM;
    int tid = threadIdx.x;
    int rg = tid >> 4, cg = tid & 15;
    int r0 = rg * 4, c0 = cg * 8;
    int lrow = tid >> 2, lq = tid & 3;

    float acc[4][8] = {};
    float tacc = 0.f;

    for (int k0 = 0; k0 < INDIM; k0 += BK) {
        __syncthreads();
        stage_x(feats, INDIM, brow, k0, N, tid, xt);
        stage_wT(Win, INDIM, k0, tid, wt);
        __syncthreads();
        tacc += lora_part(xt, Ain, INDIM, k0, lrow, lq);
        mm_inner(xt, wt, r0, c0, acc);
    }
    ts[lrow][lq] = tacc;
    __syncthreads();

#pragma unroll
    for (int i = 0; i < 4; ++i) {
        int row = brow + r0 + i;
        if (row >= N) break;
        float4 tq = *(const float4*)&ts[r0 + i][0];
        int pos = (row < PELEN) ? row : (PELEN - 1);
        const float* per = pe + (size_t)pos * HDIM;
        float o[8];
#pragma unroll
        for (int j = 0; j < 8; ++j) {
            int c = c0 + j;
            float lo = tq.x * Bin[c * RANK + 0] + tq.y * Bin[c * RANK + 1]
                     + tq.z * Bin[c * RANK + 2] + tq.w * Bin[c * RANK + 3];
            o[j] = acc[i][j] + bin[c] + per[c] + SCALING_F * lo;
        }
        float* ho = h + (size_t)row * HDIM + c0;
        *(float4*)(ho)     = make_float4(o[0], o[1], o[2], o[3]);
        *(float4*)(ho + 4) = make_float4(o[4], o[5], o[6], o[7]);
    }
}

// ================= fused layer =================
// h += gelu(LN(agg@gW + gb + h@lW.T + lb + SCALING*(h@lA.T)@lB.T))

__global__ __launch_bounds__(256) void layer_kernel(
        float* __restrict__ h, const float* __restrict__ agg,
        const float* __restrict__ gW, const float* __restrict__ gb,
        const float* __restrict__ lWp, const float* __restrict__ lbp,
        const float* __restrict__ lAp, const float* __restrict__ lBp,
        const float* __restrict__ gammap, const float* __restrict__ betap, int N) {
    __shared__ float xt[BK][XT_LD];
    __shared__ float wt[BK][WT_LD];
    __shared__ float ts[BM][RANK];
    int brow = blockIdx.x * BM;
    int tid = threadIdx.x;
    int rg = tid >> 4, cg = tid & 15;
    int r0 = rg * 4, c0 = cg * 8;
    int lrow = tid >> 2, lq = tid & 3;

    float acc[4][8] = {};
    float tacc = 0.f;

    // pass 1: agg @ gW  (gW is [K][128] direct)
    for (int k0 = 0; k0 < HDIM; k0 += BK) {
        __syncthreads();
        stage_x(agg, HDIM, brow, k0, N, tid, xt);
        stage_wD(gW, k0, tid, wt);
        __syncthreads();
        mm_inner(xt, wt, r0, c0, acc);
    }
    // pass 2: h @ lW.T  (+ lora partials on h)
    for (int k0 = 0; k0 < HDIM; k0 += BK) {
        __syncthreads();
        stage_x(h, HDIM, brow, k0, N, tid, xt);
        stage_wT(lWp, HDIM, k0, tid, wt);
        __syncthreads();
        tacc += lora_part(xt, lAp, HDIM, k0, lrow, lq);
        mm_inner(xt, wt, r0, c0, acc);
    }
    ts[lrow][lq] = tacc;
    __syncthreads();

#pragma unroll
    for (int i = 0; i < 4; ++i) {
        int row = brow + r0 + i;
        if (row >= N) continue;
        float4 tq = *(const float4*)&ts[r0 + i][0];
        float val[8];
#pragma unroll
        for (int j = 0; j < 8; ++j) {
            int c = c0 + j;
            float lo = tq.x * lBp[c * RANK + 0] + tq.y * lBp[c * RANK + 1]
                     + tq.z * lBp[c * RANK + 2] + tq.w * lBp[c * RANK + 3];
            val[j] = acc[i][j] + gb[c] + lbp[c] + SCALING_F * lo;
        }
        // LayerNorm across the 16 cg lanes (each holds 8 of 128)
        float ssum = 0.f;
#pragma unroll
        for (int j = 0; j < 8; ++j) ssum += val[j];
#pragma unroll
        for (int m = 8; m >= 1; m >>= 1) ssum += __shfl_xor(ssum, m);
        float mu = ssum * (1.0f / HDIM);
        float vsum = 0.f;
#pragma unroll
        for (int j = 0; j < 8; ++j) { float d = val[j] - mu; vsum += d * d; }
#pragma unroll
        for (int m = 8; m >= 1; m >>= 1) vsum += __shfl_xor(vsum, m);
        float rstd = rsqrtf(vsum * (1.0f / HDIM) + EPS_LN);

        float* ho = h + (size_t)row * HDIM + c0;
        float4 h0 = *(const float4*)(ho);
        float4 h1 = *(const float4*)(ho + 4);
        float hold[8] = {h0.x, h0.y, h0.z, h0.w, h1.x, h1.y, h1.z, h1.w};
        float o[8];
#pragma unroll
        for (int j = 0; j < 8; ++j) {
            int c = c0 + j;
            float y = (val[j] - mu) * rstd * gammap[c] + betap[c];
            float g = 0.5f * y * (1.0f + erff(y * 0.70710678118654752f));
            o[j] = hold[j] + g;
        }
        *(float4*)(ho)     = make_float4(o[0], o[1], o[2], o[3]);
        *(float4*)(ho + 4) = make_float4(o[4], o[5], o[6], o[7]);
    }
}

// ================= output projection =================

__global__ __launch_bounds__(256) void out_kernel(
        const float* __restrict__ h,
        const float* __restrict__ W, const float* __restrict__ b,
        const float* __restrict__ A, const float* __restrict__ B,
        float* __restrict__ out, int N) {
    __shared__ float xt[BK][XT_LD];
    __shared__ float wt[BK][WT_LD];
    __shared__ float ts[BM][RANK];
    int brow = blockIdx.x * BM;
    int tid = threadIdx.x;
    int rg = tid >> 4, cg = tid & 15;
    int r0 = rg * 4, c0 = cg * 8;
    int lrow = tid >> 2, lq = tid & 3;

    float acc[4][8] = {};
    float tacc = 0.f;

    for (int k0 = 0; k0 < HDIM; k0 += BK) {
        __syncthreads();
        stage_x(h, HDIM, brow, k0, N, tid, xt);
        stage_wT(W, HDIM, k0, tid, wt);
        __syncthreads();
        tacc += lora_part(xt, A, HDIM, k0, lrow, lq);
        mm_inner(xt, wt, r0, c0, acc);
    }
    ts[lrow][lq] = tacc;
    __syncthreads();

#pragma unroll
    for (int i = 0; i < 4; ++i) {
        int row = brow + r0 + i;
        if (row >= N) break;
        float4 tq = *(const float4*)&ts[r0 + i][0];
        float o[8];
#pragma unroll
        for (int j = 0; j < 8; ++j) {
            int c = c0 + j;
            float lo = tq.x * B[c * RANK + 0] + tq.y * B[c * RANK + 1]
                     + tq.z * B[c * RANK + 2] + tq.w * B[c * RANK + 3];
            o[j] = acc[i][j] + b[c] + SCALING_F * lo;
        }
        float* oo = out + (size_t)row * HDIM + c0;
        *(float4*)(oo)     = make_float4(o[0], o[1], o[2], o[3]);
        *(float4*)(oo + 4) = make_float4(o[4], o[5], o[6], o[7]);
    }
}

// ================= launch =================

extern "C" void kernel_launch(void* const* d_in, const int* in_sizes, int n_in,
                              void* d_out, int out_size, void* d_ws, size_t ws_size,
                              hipStream_t stream) {
    const float* features = (const float*)d_in[0];
    const int*   esrc     = (const int*)d_in[1];
    const int*   edst     = (const int*)d_in[2];
    const float* pe       = (const float*)d_in[3];
    const float* W_in     = (const float*)d_in[4];
    const float* b_in     = (const float*)d_in[5];
    const float* A_in     = (const float*)d_in[6];
    const float* B_in     = (const float*)d_in[7];
    const float* gnn_W    = (const float*)d_in[8];
    const float* gnn_b    = (const float*)d_in[9];
    const float* lW       = (const float*)d_in[10];
    const float* lb       = (const float*)d_in[11];
    const float* lA       = (const float*)d_in[12];
    const float* lB       = (const float*)d_in[13];
    const float* gamma    = (const float*)d_in[14];
    const float* beta     = (const float*)d_in[15];
    const float* W_out    = (const float*)d_in[16];
    const float* b_out    = (const float*)d_in[17];
    const float* A_out    = (const float*)d_in[18];
    const float* B_out    = (const float*)d_in[19];

    int N = in_sizes[0] / INDIM;   // 100000
    int E = in_sizes[1];           // 1,700,000
    int NB = (N + 255) / 256;

    // workspace layout
    char* ws = (char*)d_ws;
    float* h       = (float*)ws;                               // N*H
    float* agg     = h + (size_t)N * HDIM;                     // N*H
    int*   dego    = (int*)(agg + (size_t)N * HDIM);           // N
    int*   degi    = dego + N;                                 // N
    float* nout    = (float*)(degi + N);                       // N
    float* nin     = nout + N;                                 // N
    int*   row_ptr = (int*)(nin + N);                          // N+1
    int*   cursor  = row_ptr + N + 1;                          // N
    int*   sincl   = cursor + N;                               // N
    int*   bsum    = sincl + N;                                // NB
    int*   csr_src = bsum + NB;                                // E

    hipMemsetAsync(dego, 0, 2 * (size_t)N * sizeof(int), stream);
    deg_kernel<<<(E + 255) / 256, 256, 0, stream>>>(esrc, edst, dego, degi, E);
    norm_kernel<<<NB, 256, 0, stream>>>(dego, degi, nout, nin, N);

    scan1_kernel<<<NB, 256, 0, stream>>>(degi, sincl, bsum, N);
    scan2_kernel<<<1, 512, 0, stream>>>(bsum, NB);
    scan3_kernel<<<NB, 256, 0, stream>>>(degi, sincl, bsum, row_ptr, cursor, N);
    place_kernel<<<(E + 255) / 256, 256, 0, stream>>>(esrc, edst, cursor, csr_src, E);

    int gemm_grid = (N + BM - 1) / BM;
    input_kernel<<<gemm_grid, 256, 0, stream>>>(features, pe, W_in, b_in, A_in, B_in, h, N);

    for (int i = 0; i < NLAYER; ++i) {
        gather_kernel<<<(N + 3) / 4, 256, 0, stream>>>(h, nout, nin, row_ptr, csr_src, agg, N);
        layer_kernel<<<gemm_grid, 256, 0, stream>>>(
            h, agg,
            gnn_W + (size_t)i * HDIM * HDIM, gnn_b + (size_t)i * HDIM,
            lW + (size_t)i * HDIM * HDIM, lb + (size_t)i * HDIM,
            lA + (size_t)i * RANK * HDIM, lB + (size_t)i * HDIM * RANK,
            gamma + (size_t)i * HDIM, beta + (size_t)i * HDIM, N);
    }

    out_kernel<<<gemm_grid, 256, 0, stream>>>(h, W_out, b_out, A_out, B_out, (float*)d_out, N);
}